// Round 4
// baseline (932.864 us; speedup 1.0000x reference)
//
#include <hip/hip_runtime.h>
#include <cstdint>

#define BSZ 512
#define NG 5
#define NEL 32
#define IN_C 5
#define HC 64
#define NN (BSZ * NG * NEL)   // 81920 nodes
#define NE (NN * 16)          // 1310720 edges
#define NC 3
#define KTOT (NG * NEL * HC)  // 10240

__device__ __forceinline__ float bcast(float v, int l) {
  return __int_as_float(__builtin_amdgcn_readlane(__float_as_int(v), l));
}

__device__ __forceinline__ ushort bf16r(float f) {   // RNE f32->bf16
  unsigned u = __float_as_uint(f);
  return (ushort)((u + 0x7FFFu + ((u >> 16) & 1u)) >> 16);
}

__device__ __forceinline__ float bf16f(ushort s) {
  return __uint_as_float(((unsigned)s) << 16);
}

__device__ __forceinline__ float sigmoidf_(float x) {
  return 1.0f / (1.0f + __expf(-x));
}

__device__ __forceinline__ float tanhf_(float x) {
  x = fminf(fmaxf(x, -15.0f), 15.0f);
  float e = __expf(2.0f * x);
  return (e - 1.0f) / (e + 1.0f);
}

// h[n][c] = c < 5 ? x[n][c] : 0
__global__ void k_init(const float* __restrict__ x, float* __restrict__ h) {
  int idx = blockIdx.x * 256 + threadIdx.x;
  int n = idx >> 6, c = idx & 63;
  h[idx] = (c < IN_C) ? x[n * IN_C + c] : 0.0f;
}

// ---------------- CSR build ----------------
__global__ void k_zero_i(int* __restrict__ p) {
  p[blockIdx.x * 256 + threadIdx.x] = 0;
}

__global__ void k_hist(const int* __restrict__ ei, int* __restrict__ cnt) {
  int e = blockIdx.x * 256 + threadIdx.x;
  atomicAdd(&cnt[ei[NE + e]], 1);
}

__global__ void k_scan1(const int* __restrict__ cnt, int* __restrict__ off,
                        int* __restrict__ bsum) {
  __shared__ int s[256];
  int t = threadIdx.x;
  int i = blockIdx.x * 256 + t;
  int v = cnt[i];
  s[t] = v;
  __syncthreads();
  for (int d = 1; d < 256; d <<= 1) {
    int x = (t >= d) ? s[t - d] : 0;
    __syncthreads();
    s[t] += x;
    __syncthreads();
  }
  off[i] = s[t] - v;  // exclusive
  if (t == 255) bsum[blockIdx.x] = s[255];
}

__global__ void k_scan2(int* __restrict__ bsum) {
  __shared__ int s[320];
  int t = threadIdx.x;
  if (t < 320) s[t] = bsum[t];
  __syncthreads();
  if (t == 0) {
    int run = 0;
    for (int i = 0; i < 320; ++i) { int x = s[i]; s[i] = run; run += x; }
  }
  __syncthreads();
  if (t < 320) bsum[t] = s[t];
}

__global__ void k_scan3(int* __restrict__ off, const int* __restrict__ bsum) {
  int i = blockIdx.x * 256 + threadIdx.x;
  off[i] += bsum[blockIdx.x];
}

// scatter edges into CSR slots; off[n] mutates into row-end pointer
__global__ void k_scatter(const int* __restrict__ ei, const float* __restrict__ ea,
                          int* __restrict__ off, int2* __restrict__ csr) {
  int e = blockIdx.x * 256 + threadIdx.x;
  int dst = ei[NE + e];
  int slot = atomicAdd(&off[dst], 1);
  csr[slot] = make_int2(ei[e], __float_as_int(ea[e]));
}

// ---------------- per-layer kernels ----------------

// m16 = bf16(h @ Wg); wave-per-node, Wg column in regs
__global__ void k_gemm64(const float* __restrict__ h, const float* __restrict__ Wg,
                         ushort* __restrict__ m16) {
  const int lane = threadIdx.x & 63;
  const int gw = (blockIdx.x * blockDim.x + threadIdx.x) >> 6;
  const int nw = (gridDim.x * blockDim.x) >> 6;
  float wcol[64];
#pragma unroll
  for (int k = 0; k < 64; ++k) wcol[k] = Wg[k * 64 + lane];
  for (int n = gw; n < NN; n += nw) {
    float hv = h[n * 64 + lane];
    float acc = 0.0f;
#pragma unroll
    for (int k = 0; k < 64; ++k) acc = fmaf(bcast(hv, k), wcol[k], acc);
    m16[n * 64 + lane] = bf16r(acc);
  }
}

// Fused: aggr-row (register) = sum_{edges} m16[src]*w, then gi = aggr @ wih.T + bih
// wave-per-node; wih rows (r,z,n for this lane) = 192 VGPRs; gi stored bf16.
__global__ void __launch_bounds__(256, 2) k_aggr_gi(
    const int* __restrict__ off, const int* __restrict__ cnt,
    const int2* __restrict__ csr, const ushort* __restrict__ m16,
    const float* __restrict__ wih, const float* __restrict__ bih,
    ushort* __restrict__ gir, ushort* __restrict__ giz, ushort* __restrict__ gin) {
  const int lane = threadIdx.x & 63;
  int wv = (blockIdx.x * 256 + threadIdx.x) >> 6;
  const int nw = (gridDim.x * 256) >> 6;
  float wr[64], wz[64], wn[64];
#pragma unroll
  for (int k = 0; k < 64; ++k) {
    wr[k] = wih[lane * 64 + k];
    wz[k] = wih[(64 + lane) * 64 + k];
    wn[k] = wih[(128 + lane) * 64 + k];
  }
  const float br = bih[lane], bz = bih[64 + lane], bn = bih[128 + lane];
  for (int n = wv; n < NN; n += nw) {
    const int r1 = __builtin_amdgcn_readfirstlane(off[n]);  // row end
    const int c = __builtin_amdgcn_readfirstlane(cnt[n]);
    const int r0 = r1 - c;
    // whole CSR row fetched lane-parallel (row len <= 64 in practice)
    int2 ed = make_int2(0, 0);
    if (r0 + lane < r1) ed = csr[r0 + lane];
    const int cc = c > 64 ? 64 : c;
    float acc = 0.0f;
    int i = 0;
    for (; i + 8 <= cc; i += 8) {
      int s0 = __builtin_amdgcn_readlane(ed.x, i + 0);
      int s1 = __builtin_amdgcn_readlane(ed.x, i + 1);
      int s2 = __builtin_amdgcn_readlane(ed.x, i + 2);
      int s3 = __builtin_amdgcn_readlane(ed.x, i + 3);
      int s4 = __builtin_amdgcn_readlane(ed.x, i + 4);
      int s5 = __builtin_amdgcn_readlane(ed.x, i + 5);
      int s6 = __builtin_amdgcn_readlane(ed.x, i + 6);
      int s7 = __builtin_amdgcn_readlane(ed.x, i + 7);
      float m0 = bf16f(m16[(size_t)s0 * 64 + lane]);
      float m1 = bf16f(m16[(size_t)s1 * 64 + lane]);
      float m2 = bf16f(m16[(size_t)s2 * 64 + lane]);
      float m3 = bf16f(m16[(size_t)s3 * 64 + lane]);
      float m4 = bf16f(m16[(size_t)s4 * 64 + lane]);
      float m5 = bf16f(m16[(size_t)s5 * 64 + lane]);
      float m6 = bf16f(m16[(size_t)s6 * 64 + lane]);
      float m7 = bf16f(m16[(size_t)s7 * 64 + lane]);
      acc = fmaf(m0, __int_as_float(__builtin_amdgcn_readlane(ed.y, i + 0)), acc);
      acc = fmaf(m1, __int_as_float(__builtin_amdgcn_readlane(ed.y, i + 1)), acc);
      acc = fmaf(m2, __int_as_float(__builtin_amdgcn_readlane(ed.y, i + 2)), acc);
      acc = fmaf(m3, __int_as_float(__builtin_amdgcn_readlane(ed.y, i + 3)), acc);
      acc = fmaf(m4, __int_as_float(__builtin_amdgcn_readlane(ed.y, i + 4)), acc);
      acc = fmaf(m5, __int_as_float(__builtin_amdgcn_readlane(ed.y, i + 5)), acc);
      acc = fmaf(m6, __int_as_float(__builtin_amdgcn_readlane(ed.y, i + 6)), acc);
      acc = fmaf(m7, __int_as_float(__builtin_amdgcn_readlane(ed.y, i + 7)), acc);
    }
    for (; i < cc; ++i) {
      int src = __builtin_amdgcn_readlane(ed.x, i);
      float wgt = __int_as_float(__builtin_amdgcn_readlane(ed.y, i));
      acc = fmaf(bf16f(m16[(size_t)src * 64 + lane]), wgt, acc);
    }
    for (int j = 64; j < c; ++j) {  // astronomically rare (row > 64)
      int2 e2 = csr[r0 + j];
      acc = fmaf(bf16f(m16[(size_t)e2.x * 64 + lane]), __int_as_float(e2.y), acc);
    }
    // gi = acc-row @ wih.T + bih
    float gr = br, gz = bz, gn = bn;
#pragma unroll
    for (int k = 0; k < 64; ++k) {
      float av = bcast(acc, k);
      gr = fmaf(av, wr[k], gr);
      gz = fmaf(av, wz[k], gz);
      gn = fmaf(av, wn[k], gn);
    }
    gir[(size_t)n * 64 + lane] = bf16r(gr);
    giz[(size_t)n * 64 + lane] = bf16r(gz);
    gin[(size_t)n * 64 + lane] = bf16r(gn);
  }
}

// GRU finish: gh = h @ whh.T + bhh (192 weight VGPRs), activations, h update
__global__ void __launch_bounds__(256, 2) k_gru_fin(
    float* __restrict__ h, const ushort* __restrict__ gir,
    const ushort* __restrict__ giz, const ushort* __restrict__ gin,
    const float* __restrict__ whh, const float* __restrict__ bhh) {
  const int lane = threadIdx.x & 63;
  int wv = (blockIdx.x * 256 + threadIdx.x) >> 6;
  const int nw = (gridDim.x * 256) >> 6;
  float vr[64], vz[64], vn[64];
#pragma unroll
  for (int k = 0; k < 64; ++k) {
    vr[k] = whh[lane * 64 + k];
    vz[k] = whh[(64 + lane) * 64 + k];
    vn[k] = whh[(128 + lane) * 64 + k];
  }
  const float cr = bhh[lane], cz = bhh[64 + lane], cn = bhh[128 + lane];
  for (int n = wv; n < NN; n += nw) {
    const size_t idx = (size_t)n * 64 + lane;
    float hv = h[idx];
    float gr = bf16f(gir[idx]);
    float gz = bf16f(giz[idx]);
    float gn = bf16f(gin[idx]);
    float hr = cr, hz = cz, hn = cn;
#pragma unroll
    for (int k = 0; k < 64; ++k) {
      float hb = bcast(hv, k);
      hr = fmaf(hb, vr[k], hr);
      hz = fmaf(hb, vz[k], hz);
      hn = fmaf(hb, vn[k], hn);
    }
    float r = sigmoidf_(gr + hr);
    float z = sigmoidf_(gz + hz);
    float nv = tanhf_(gn + r * hn);
    h[idx] = (1.0f - z) * nv + z * hv;
  }
}

// z1pre[bs][c] += sum over a K slice of rearranged(h) @ W1.T
__global__ void k_mlp1(const float* __restrict__ h, const float* __restrict__ W1,
                       float* __restrict__ z1) {
  __shared__ float Alds[8 * 512];
  const int tid = threadIdx.x;
  const int grp = blockIdx.x >> 2;   // 0..63
  const int sl = blockIdx.x & 3;     // K slice
  const int bs0 = grp * 8;
  const int c = tid & 63;
  const int w = tid >> 6;            // 0..3
  float acc0 = 0.0f, acc1 = 0.0f;
  for (int ch = 0; ch < 5; ++ch) {
    __syncthreads();
    const int kbase = sl * 2560 + ch * 512;
    for (int idx = tid; idx < 8 * 512; idx += 256) {
      int j = idx >> 9, kk = idx & 511;
      int kg = kbase + kk;
      int e = kg / 320;
      int r = kg - e * 320;
      int g = r >> 6, f = r & 63;
      int n = (bs0 + j) * (NG * NEL) + g * NEL + e;
      Alds[idx] = h[(size_t)n * 64 + f];
    }
    __syncthreads();
    const float* w1p = W1 + (size_t)c * KTOT + kbase;
#pragma unroll 8
    for (int kk = 0; kk < 512; ++kk) {
      float wv = w1p[kk];
      acc0 = fmaf(Alds[w * 512 + kk], wv, acc0);
      acc1 = fmaf(Alds[(w + 4) * 512 + kk], wv, acc1);
    }
  }
  unsafeAtomicAdd(&z1[(bs0 + w) * 64 + c], acc0);
  unsafeAtomicAdd(&z1[(bs0 + w + 4) * 64 + c], acc1);
}

// relu(z1+b1) -> 32 -> 16 -> 3 -> softmax; wave-per-batch-row
__global__ void k_tail(const float* __restrict__ z1, const float* __restrict__ b1,
                       const float* __restrict__ W2, const float* __restrict__ b2,
                       const float* __restrict__ W3, const float* __restrict__ b3,
                       const float* __restrict__ W4, const float* __restrict__ b4,
                       float* __restrict__ out) {
  const int lane = threadIdx.x & 63;
  const int bs = blockIdx.x * 4 + (threadIdx.x >> 6);
  float zv = fmaxf(z1[(size_t)bs * 64 + lane] + b1[lane], 0.0f);
  const int c2 = lane & 31;
  float acc2 = b2[c2];
#pragma unroll
  for (int k = 0; k < 64; ++k) acc2 = fmaf(bcast(zv, k), W2[c2 * 64 + k], acc2);
  acc2 = fmaxf(acc2, 0.0f);
  const int c3 = lane & 15;
  float acc3 = b3[c3];
#pragma unroll
  for (int k = 0; k < 32; ++k) acc3 = fmaf(bcast(acc2, k), W3[c3 * 32 + k], acc3);
  acc3 = fmaxf(acc3, 0.0f);
  float l0 = b4[0], l1 = b4[1], l2 = b4[2];
#pragma unroll
  for (int k = 0; k < 16; ++k) {
    float v = bcast(acc3, k);
    l0 = fmaf(v, W4[k], l0);
    l1 = fmaf(v, W4[16 + k], l1);
    l2 = fmaf(v, W4[32 + k], l2);
  }
  float mx = fmaxf(l0, fmaxf(l1, l2));
  float e0 = __expf(l0 - mx), e1 = __expf(l1 - mx), e2 = __expf(l2 - mx);
  float inv = 1.0f / (e0 + e1 + e2);
  if (lane == 0) {
    out[bs * 3 + 0] = e0 * inv;
    out[bs * 3 + 1] = e1 * inv;
    out[bs * 3 + 2] = e2 * inv;
  }
}

extern "C" void kernel_launch(void* const* d_in, const int* in_sizes, int n_in,
                              void* d_out, int out_size, void* d_ws, size_t ws_size,
                              hipStream_t stream) {
  const float* x = (const float*)d_in[0];
  const int* ei = (const int*)d_in[1];
  const float* ea = (const float*)d_in[2];
  const float* Wg = (const float*)d_in[3];
  const float* wih = (const float*)d_in[4];
  const float* whh = (const float*)d_in[5];
  const float* bih = (const float*)d_in[6];
  const float* bhh = (const float*)d_in[7];
  const float* W1 = (const float*)d_in[8];
  const float* b1 = (const float*)d_in[9];
  const float* W2 = (const float*)d_in[10];
  const float* b2 = (const float*)d_in[11];
  const float* W3 = (const float*)d_in[12];
  const float* b3 = (const float*)d_in[13];
  const float* W4 = (const float*)d_in[14];
  const float* b4 = (const float*)d_in[15];
  float* out = (float*)d_out;

  // workspace layout (all segments 8B-aligned by construction)
  float* h = (float*)d_ws;                          // NN*64 f32
  float* z1 = h + (size_t)NN * 64;                  // BSZ*64 f32
  int* cnt = (int*)(z1 + BSZ * 64);                 // NN
  int* off = cnt + NN;                              // NN
  int* bsum = off + NN;                             // 512
  int2* csr = (int2*)(bsum + 512);                  // NE int2
  ushort* m16 = (ushort*)(csr + NE);                // NN*64
  ushort* gir = m16 + (size_t)NN * 64;              // NN*64
  ushort* giz = gir + (size_t)NN * 64;              // NN*64
  ushort* gin = giz + (size_t)NN * 64;              // NN*64

  // --- CSR build (once per launch) ---
  k_zero_i<<<NN / 256, 256, 0, stream>>>(cnt);
  k_hist<<<NE / 256, 256, 0, stream>>>(ei, cnt);
  k_scan1<<<NN / 256, 256, 0, stream>>>(cnt, off, bsum);
  k_scan2<<<1, 512, 0, stream>>>(bsum);
  k_scan3<<<NN / 256, 256, 0, stream>>>(off, bsum);
  k_scatter<<<NE / 256, 256, 0, stream>>>(ei, ea, off, csr);  // off -> row ends

  hipMemsetAsync(z1, 0, BSZ * 64 * sizeof(float), stream);
  k_init<<<NN * 64 / 256, 256, 0, stream>>>(x, h);
  for (int layer = 0; layer < 2; ++layer) {
    k_gemm64<<<1024, 256, 0, stream>>>(h, Wg + layer * 64 * 64, m16);
    k_aggr_gi<<<2048, 256, 0, stream>>>(off, cnt, csr, m16, wih, bih, gir, giz, gin);
    k_gru_fin<<<2048, 256, 0, stream>>>(h, gir, giz, gin, whh, bhh);
  }
  k_mlp1<<<256, 256, 0, stream>>>(h, W1, z1);
  k_tail<<<BSZ / 4, 256, 0, stream>>>(z1, b1, W2, b2, W3, b3, W4, b4, out);
}

// Round 5
// 543.545 us; speedup vs baseline: 1.7163x; 1.7163x over previous
//
#include <hip/hip_runtime.h>
#include <cstdint>

#define BSZ 512
#define NG 5
#define NEL 32
#define IN_C 5
#define HC 64
#define NN (BSZ * NG * NEL)   // 81920 nodes
#define NE (NN * 16)          // 1310720 edges
#define NC 3
#define KTOT (NG * NEL * HC)  // 10240

typedef __attribute__((ext_vector_type(8))) short bf16x8;
typedef __attribute__((ext_vector_type(4))) float f32x4;

__device__ __forceinline__ float bcast(float v, int l) {
  return __int_as_float(__builtin_amdgcn_readlane(__float_as_int(v), l));
}

__device__ __forceinline__ ushort bf16r(float f) {   // RNE f32->bf16
  unsigned u = __float_as_uint(f);
  return (ushort)((u + 0x7FFFu + ((u >> 16) & 1u)) >> 16);
}

__device__ __forceinline__ float bf16f(ushort s) {
  return __uint_as_float(((unsigned)s) << 16);
}

__device__ __forceinline__ bf16x8 packf4(float4 x, float4 y) {
  bf16x8 r;
  r[0] = (short)bf16r(x.x); r[1] = (short)bf16r(x.y);
  r[2] = (short)bf16r(x.z); r[3] = (short)bf16r(x.w);
  r[4] = (short)bf16r(y.x); r[5] = (short)bf16r(y.y);
  r[6] = (short)bf16r(y.z); r[7] = (short)bf16r(y.w);
  return r;
}

__device__ __forceinline__ float sigmoidf_(float x) {
  return 1.0f / (1.0f + __expf(-x));
}

__device__ __forceinline__ float tanhf_(float x) {
  x = fminf(fmaxf(x, -15.0f), 15.0f);
  float e = __expf(2.0f * x);
  return (e - 1.0f) / (e + 1.0f);
}

// h[n][c] = c < 5 ? x[n][c] : 0
__global__ void k_init(const float* __restrict__ x, float* __restrict__ h) {
  int idx = blockIdx.x * 256 + threadIdx.x;
  int n = idx >> 6, c = idx & 63;
  h[idx] = (c < IN_C) ? x[n * IN_C + c] : 0.0f;
}

// ---------------- CSR build ----------------
__global__ void k_zero_i(int* __restrict__ p) {
  p[blockIdx.x * 256 + threadIdx.x] = 0;
}

__global__ void k_hist(const int* __restrict__ ei, int* __restrict__ cnt) {
  int e = blockIdx.x * 256 + threadIdx.x;
  atomicAdd(&cnt[ei[NE + e]], 1);
}

__global__ void k_scan1(const int* __restrict__ cnt, int* __restrict__ off,
                        int* __restrict__ bsum) {
  __shared__ int s[256];
  int t = threadIdx.x;
  int i = blockIdx.x * 256 + t;
  int v = cnt[i];
  s[t] = v;
  __syncthreads();
  for (int d = 1; d < 256; d <<= 1) {
    int x = (t >= d) ? s[t - d] : 0;
    __syncthreads();
    s[t] += x;
    __syncthreads();
  }
  off[i] = s[t] - v;  // exclusive
  if (t == 255) bsum[blockIdx.x] = s[255];
}

__global__ void k_scan2(int* __restrict__ bsum) {
  __shared__ int s[320];
  int t = threadIdx.x;
  if (t < 320) s[t] = bsum[t];
  __syncthreads();
  if (t == 0) {
    int run = 0;
    for (int i = 0; i < 320; ++i) { int x = s[i]; s[i] = run; run += x; }
  }
  __syncthreads();
  if (t < 320) bsum[t] = s[t];
}

__global__ void k_scan3(int* __restrict__ off, const int* __restrict__ bsum) {
  int i = blockIdx.x * 256 + threadIdx.x;
  off[i] += bsum[blockIdx.x];
}

// scatter edges into CSR slots; off[n] mutates into row-end pointer
__global__ void k_scatter(const int* __restrict__ ei, const float* __restrict__ ea,
                          int* __restrict__ off, int2* __restrict__ csr) {
  int e = blockIdx.x * 256 + threadIdx.x;
  int dst = ei[NE + e];
  int slot = atomicAdd(&off[dst], 1);
  csr[slot] = make_int2(ei[e], __float_as_int(ea[e]));
}

// ---------------- per-layer kernels ----------------

// m16 = bf16(h @ Wg); wave-per-node, Wg column in regs
__global__ void k_gemm64(const float* __restrict__ h, const float* __restrict__ Wg,
                         ushort* __restrict__ m16) {
  const int lane = threadIdx.x & 63;
  const int gw = (blockIdx.x * blockDim.x + threadIdx.x) >> 6;
  const int nw = (gridDim.x * blockDim.x) >> 6;
  float wcol[64];
#pragma unroll
  for (int k = 0; k < 64; ++k) wcol[k] = Wg[k * 64 + lane];
  for (int n = gw; n < NN; n += nw) {
    float hv = h[n * 64 + lane];
    float acc = 0.0f;
#pragma unroll
    for (int k = 0; k < 64; ++k) acc = fmaf(bcast(hv, k), wcol[k], acc);
    m16[n * 64 + lane] = bf16r(acc);
  }
}

// aggr16[n] = bf16( sum over CSR row n of m16[src]*w ); minimal, occupancy-max
__global__ void k_aggregate(const int* __restrict__ off, const int* __restrict__ cnt,
                            const int2* __restrict__ csr, const ushort* __restrict__ m16,
                            ushort* __restrict__ aggr16) {
  const int lane = threadIdx.x & 63;
  int wv = (blockIdx.x * 256 + threadIdx.x) >> 6;
  const int nw = (gridDim.x * 256) >> 6;
  for (int n = wv; n < NN; n += nw) {
    const int r1 = __builtin_amdgcn_readfirstlane(off[n]);  // row end
    const int c = __builtin_amdgcn_readfirstlane(cnt[n]);
    const int r0 = r1 - c;
    int2 ed = make_int2(0, 0);
    if (lane < c) ed = csr[r0 + lane];
    const int cc = c > 64 ? 64 : c;
    float acc = 0.0f;
    int i = 0;
    for (; i + 8 <= cc; i += 8) {
      int s0 = __builtin_amdgcn_readlane(ed.x, i + 0);
      int s1 = __builtin_amdgcn_readlane(ed.x, i + 1);
      int s2 = __builtin_amdgcn_readlane(ed.x, i + 2);
      int s3 = __builtin_amdgcn_readlane(ed.x, i + 3);
      int s4 = __builtin_amdgcn_readlane(ed.x, i + 4);
      int s5 = __builtin_amdgcn_readlane(ed.x, i + 5);
      int s6 = __builtin_amdgcn_readlane(ed.x, i + 6);
      int s7 = __builtin_amdgcn_readlane(ed.x, i + 7);
      float m0 = bf16f(m16[(size_t)s0 * 64 + lane]);
      float m1 = bf16f(m16[(size_t)s1 * 64 + lane]);
      float m2 = bf16f(m16[(size_t)s2 * 64 + lane]);
      float m3 = bf16f(m16[(size_t)s3 * 64 + lane]);
      float m4 = bf16f(m16[(size_t)s4 * 64 + lane]);
      float m5 = bf16f(m16[(size_t)s5 * 64 + lane]);
      float m6 = bf16f(m16[(size_t)s6 * 64 + lane]);
      float m7 = bf16f(m16[(size_t)s7 * 64 + lane]);
      acc = fmaf(m0, __int_as_float(__builtin_amdgcn_readlane(ed.y, i + 0)), acc);
      acc = fmaf(m1, __int_as_float(__builtin_amdgcn_readlane(ed.y, i + 1)), acc);
      acc = fmaf(m2, __int_as_float(__builtin_amdgcn_readlane(ed.y, i + 2)), acc);
      acc = fmaf(m3, __int_as_float(__builtin_amdgcn_readlane(ed.y, i + 3)), acc);
      acc = fmaf(m4, __int_as_float(__builtin_amdgcn_readlane(ed.y, i + 4)), acc);
      acc = fmaf(m5, __int_as_float(__builtin_amdgcn_readlane(ed.y, i + 5)), acc);
      acc = fmaf(m6, __int_as_float(__builtin_amdgcn_readlane(ed.y, i + 6)), acc);
      acc = fmaf(m7, __int_as_float(__builtin_amdgcn_readlane(ed.y, i + 7)), acc);
    }
    for (; i < cc; ++i) {
      int src = __builtin_amdgcn_readlane(ed.x, i);
      float wgt = __int_as_float(__builtin_amdgcn_readlane(ed.y, i));
      acc = fmaf(bf16f(m16[(size_t)src * 64 + lane]), wgt, acc);
    }
    for (int j = 64; j < c; ++j) {  // rare overflow
      int2 e2 = csr[r0 + j];
      acc = fmaf(bf16f(m16[(size_t)e2.x * 64 + lane]), __int_as_float(e2.y), acc);
    }
    aggr16[(size_t)n * 64 + lane] = bf16r(acc);
  }
}

// GRU via MFMA: gi = aggr@wih.T, gh = h@whh.T, gates, h update.
// Block = 4 waves over one 16-node group; wave w owns gate cols 16w..16w+15.
// Layouts (mfma_f32_16x16x32_bf16): A[m=lane&15][k=quad*8+j],
// B[k=quad*8+j][n=lane&15], C/D col=lane&15 row=quad*4+reg.
__global__ void __launch_bounds__(256) k_gru_mfma(
    const ushort* __restrict__ aggr16, float* __restrict__ h,
    const float* __restrict__ wih, const float* __restrict__ whh,
    const float* __restrict__ bih, const float* __restrict__ bhh) {
  const int lane = threadIdx.x & 63;
  const int w = threadIdx.x >> 6;  // 0..3
  const int cl = lane & 15;
  const int quad = lane >> 4;
  const int c = w * 16 + cl;       // gate col 0..63

  // stage B fragments (bf16) for this wave's col slice: r/z/n x {gi, gh} x 2 K-halves
  bf16x8 BI[3][2], BH[3][2];
#pragma unroll
  for (int g3 = 0; g3 < 3; ++g3) {
    const float* wi = wih + (size_t)(g3 * 64 + c) * 64;
    const float* wh = whh + (size_t)(g3 * 64 + c) * 64;
#pragma unroll
    for (int kh = 0; kh < 2; ++kh) {
      const float* p = wi + kh * 32 + quad * 8;
      BI[g3][kh] = packf4(*(const float4*)p, *(const float4*)(p + 4));
      const float* q = wh + kh * 32 + quad * 8;
      BH[g3][kh] = packf4(*(const float4*)q, *(const float4*)(q + 4));
    }
  }
  const float br = bih[c] + bhh[c];
  const float bz = bih[64 + c] + bhh[64 + c];
  const float bni = bih[128 + c];
  const float bnh = bhh[128 + c];

  const int ngroups = NN / 16;  // 5120
  for (int g = blockIdx.x; g < ngroups; g += gridDim.x) {
    // A fragments: aggr (bf16 direct) and h (f32 -> bf16)
    const size_t arow = (size_t)(g * 16 + cl) * 64 + quad * 8;
    bf16x8 a0 = *(const bf16x8*)(aggr16 + arow);
    bf16x8 a1 = *(const bf16x8*)(aggr16 + arow + 32);
    const float* hp = h + arow;
    bf16x8 h0 = packf4(*(const float4*)hp, *(const float4*)(hp + 4));
    bf16x8 h1 = packf4(*(const float4*)(hp + 32), *(const float4*)(hp + 36));
    // old h values in D layout for the update
    float hv[4];
    const size_t obase = (size_t)(g * 16 + quad * 4) * 64 + c;
#pragma unroll
    for (int rg = 0; rg < 4; ++rg) hv[rg] = h[obase + (size_t)rg * 64];
    __syncthreads();  // all h reads done before any wave stores h

    f32x4 zero = {0.0f, 0.0f, 0.0f, 0.0f};
    f32x4 aR = zero, aZ = zero, aN = zero, hR = zero, hZ = zero, hN = zero;
    aR = __builtin_amdgcn_mfma_f32_16x16x32_bf16(a0, BI[0][0], aR, 0, 0, 0);
    aR = __builtin_amdgcn_mfma_f32_16x16x32_bf16(a1, BI[0][1], aR, 0, 0, 0);
    aZ = __builtin_amdgcn_mfma_f32_16x16x32_bf16(a0, BI[1][0], aZ, 0, 0, 0);
    aZ = __builtin_amdgcn_mfma_f32_16x16x32_bf16(a1, BI[1][1], aZ, 0, 0, 0);
    aN = __builtin_amdgcn_mfma_f32_16x16x32_bf16(a0, BI[2][0], aN, 0, 0, 0);
    aN = __builtin_amdgcn_mfma_f32_16x16x32_bf16(a1, BI[2][1], aN, 0, 0, 0);
    hR = __builtin_amdgcn_mfma_f32_16x16x32_bf16(h0, BH[0][0], hR, 0, 0, 0);
    hR = __builtin_amdgcn_mfma_f32_16x16x32_bf16(h1, BH[0][1], hR, 0, 0, 0);
    hZ = __builtin_amdgcn_mfma_f32_16x16x32_bf16(h0, BH[1][0], hZ, 0, 0, 0);
    hZ = __builtin_amdgcn_mfma_f32_16x16x32_bf16(h1, BH[1][1], hZ, 0, 0, 0);
    hN = __builtin_amdgcn_mfma_f32_16x16x32_bf16(h0, BH[2][0], hN, 0, 0, 0);
    hN = __builtin_amdgcn_mfma_f32_16x16x32_bf16(h1, BH[2][1], hN, 0, 0, 0);

#pragma unroll
    for (int rg = 0; rg < 4; ++rg) {
      float r = sigmoidf_(aR[rg] + hR[rg] + br);
      float z = sigmoidf_(aZ[rg] + hZ[rg] + bz);
      float nv = tanhf_(aN[rg] + bni + r * (hN[rg] + bnh));
      h[obase + (size_t)rg * 64] = (1.0f - z) * nv + z * hv[rg];
    }
  }
}

// z1pre[bs][c] += sum over a K slice of rearranged(h) @ W1.T
__global__ void k_mlp1(const float* __restrict__ h, const float* __restrict__ W1,
                       float* __restrict__ z1) {
  __shared__ float Alds[8 * 512];
  const int tid = threadIdx.x;
  const int grp = blockIdx.x >> 2;   // 0..63
  const int sl = blockIdx.x & 3;     // K slice
  const int bs0 = grp * 8;
  const int c = tid & 63;
  const int w = tid >> 6;            // 0..3
  float acc0 = 0.0f, acc1 = 0.0f;
  for (int ch = 0; ch < 5; ++ch) {
    __syncthreads();
    const int kbase = sl * 2560 + ch * 512;
    for (int idx = tid; idx < 8 * 512; idx += 256) {
      int j = idx >> 9, kk = idx & 511;
      int kg = kbase + kk;
      int e = kg / 320;
      int r = kg - e * 320;
      int g = r >> 6, f = r & 63;
      int n = (bs0 + j) * (NG * NEL) + g * NEL + e;
      Alds[idx] = h[(size_t)n * 64 + f];
    }
    __syncthreads();
    const float* w1p = W1 + (size_t)c * KTOT + kbase;
#pragma unroll 8
    for (int kk = 0; kk < 512; ++kk) {
      float wv = w1p[kk];
      acc0 = fmaf(Alds[w * 512 + kk], wv, acc0);
      acc1 = fmaf(Alds[(w + 4) * 512 + kk], wv, acc1);
    }
  }
  unsafeAtomicAdd(&z1[(bs0 + w) * 64 + c], acc0);
  unsafeAtomicAdd(&z1[(bs0 + w + 4) * 64 + c], acc1);
}

// relu(z1+b1) -> 32 -> 16 -> 3 -> softmax; wave-per-batch-row
__global__ void k_tail(const float* __restrict__ z1, const float* __restrict__ b1,
                       const float* __restrict__ W2, const float* __restrict__ b2,
                       const float* __restrict__ W3, const float* __restrict__ b3,
                       const float* __restrict__ W4, const float* __restrict__ b4,
                       float* __restrict__ out) {
  const int lane = threadIdx.x & 63;
  const int bs = blockIdx.x * 4 + (threadIdx.x >> 6);
  float zv = fmaxf(z1[(size_t)bs * 64 + lane] + b1[lane], 0.0f);
  const int c2 = lane & 31;
  float acc2 = b2[c2];
#pragma unroll
  for (int k = 0; k < 64; ++k) acc2 = fmaf(bcast(zv, k), W2[c2 * 64 + k], acc2);
  acc2 = fmaxf(acc2, 0.0f);
  const int c3 = lane & 15;
  float acc3 = b3[c3];
#pragma unroll
  for (int k = 0; k < 32; ++k) acc3 = fmaf(bcast(acc2, k), W3[c3 * 32 + k], acc3);
  acc3 = fmaxf(acc3, 0.0f);
  float l0 = b4[0], l1 = b4[1], l2 = b4[2];
#pragma unroll
  for (int k = 0; k < 16; ++k) {
    float v = bcast(acc3, k);
    l0 = fmaf(v, W4[k], l0);
    l1 = fmaf(v, W4[16 + k], l1);
    l2 = fmaf(v, W4[32 + k], l2);
  }
  float mx = fmaxf(l0, fmaxf(l1, l2));
  float e0 = __expf(l0 - mx), e1 = __expf(l1 - mx), e2 = __expf(l2 - mx);
  float inv = 1.0f / (e0 + e1 + e2);
  if (lane == 0) {
    out[bs * 3 + 0] = e0 * inv;
    out[bs * 3 + 1] = e1 * inv;
    out[bs * 3 + 2] = e2 * inv;
  }
}

extern "C" void kernel_launch(void* const* d_in, const int* in_sizes, int n_in,
                              void* d_out, int out_size, void* d_ws, size_t ws_size,
                              hipStream_t stream) {
  const float* x = (const float*)d_in[0];
  const int* ei = (const int*)d_in[1];
  const float* ea = (const float*)d_in[2];
  const float* Wg = (const float*)d_in[3];
  const float* wih = (const float*)d_in[4];
  const float* whh = (const float*)d_in[5];
  const float* bih = (const float*)d_in[6];
  const float* bhh = (const float*)d_in[7];
  const float* W1 = (const float*)d_in[8];
  const float* b1 = (const float*)d_in[9];
  const float* W2 = (const float*)d_in[10];
  const float* b2 = (const float*)d_in[11];
  const float* W3 = (const float*)d_in[12];
  const float* b3 = (const float*)d_in[13];
  const float* W4 = (const float*)d_in[14];
  const float* b4 = (const float*)d_in[15];
  float* out = (float*)d_out;

  // workspace layout
  float* h = (float*)d_ws;                          // NN*64 f32
  float* z1 = h + (size_t)NN * 64;                  // BSZ*64 f32
  int* cnt = (int*)(z1 + BSZ * 64);                 // NN
  int* off = cnt + NN;                              // NN
  int* bsum = off + NN;                             // 512
  int2* csr = (int2*)(bsum + 512);                  // NE int2
  ushort* m16 = (ushort*)(csr + NE);                // NN*64
  ushort* aggr16 = m16 + (size_t)NN * 64;           // NN*64

  // --- CSR build (once per launch) ---
  k_zero_i<<<NN / 256, 256, 0, stream>>>(cnt);
  k_hist<<<NE / 256, 256, 0, stream>>>(ei, cnt);
  k_scan1<<<NN / 256, 256, 0, stream>>>(cnt, off, bsum);
  k_scan2<<<1, 512, 0, stream>>>(bsum);
  k_scan3<<<NN / 256, 256, 0, stream>>>(off, bsum);
  k_scatter<<<NE / 256, 256, 0, stream>>>(ei, ea, off, csr);  // off -> row ends

  hipMemsetAsync(z1, 0, BSZ * 64 * sizeof(float), stream);
  k_init<<<NN * 64 / 256, 256, 0, stream>>>(x, h);
  for (int layer = 0; layer < 2; ++layer) {
    k_gemm64<<<1024, 256, 0, stream>>>(h, Wg + layer * 64 * 64, m16);
    k_aggregate<<<2048, 256, 0, stream>>>(off, cnt, csr, m16, aggr16);
    k_gru_mfma<<<1280, 256, 0, stream>>>(aggr16, h, wih, whh, bih, bhh);
  }
  k_mlp1<<<256, 256, 0, stream>>>(h, W1, z1);
  k_tail<<<BSZ / 4, 256, 0, stream>>>(z1, b1, W2, b2, W3, b3, W4, b4, out);
}

// Round 6
// 431.957 us; speedup vs baseline: 2.1596x; 1.2583x over previous
//
#include <hip/hip_runtime.h>
#include <cstdint>

#define BSZ 512
#define NG 5
#define NEL 32
#define IN_C 5
#define HC 64
#define NN (BSZ * NG * NEL)   // 81920 nodes
#define NE (NN * 16)          // 1310720 edges
#define NC 3
#define KTOT (NG * NEL * HC)  // 10240
#define NSLICE 16

typedef __attribute__((ext_vector_type(8))) short bf16x8;
typedef __attribute__((ext_vector_type(4))) float f32x4;

__device__ __forceinline__ float bcast(float v, int l) {
  return __int_as_float(__builtin_amdgcn_readlane(__float_as_int(v), l));
}

__device__ __forceinline__ ushort bf16r(float f) {   // RNE f32->bf16
  unsigned u = __float_as_uint(f);
  return (ushort)((u + 0x7FFFu + ((u >> 16) & 1u)) >> 16);
}

__device__ __forceinline__ float bf16f(ushort s) {
  return __uint_as_float(((unsigned)s) << 16);
}

__device__ __forceinline__ bf16x8 packf4(float4 x, float4 y) {
  bf16x8 r;
  r[0] = (short)bf16r(x.x); r[1] = (short)bf16r(x.y);
  r[2] = (short)bf16r(x.z); r[3] = (short)bf16r(x.w);
  r[4] = (short)bf16r(y.x); r[5] = (short)bf16r(y.y);
  r[6] = (short)bf16r(y.z); r[7] = (short)bf16r(y.w);
  return r;
}

__device__ __forceinline__ float sigmoidf_(float x) {
  return 1.0f / (1.0f + __expf(-x));
}

__device__ __forceinline__ float tanhf_(float x) {
  x = fminf(fmaxf(x, -15.0f), 15.0f);
  float e = __expf(2.0f * x);
  return (e - 1.0f) / (e + 1.0f);
}

// h[n][c] = c < 5 ? x[n][c] : 0
__global__ void k_init(const float* __restrict__ x, float* __restrict__ h) {
  int idx = blockIdx.x * 256 + threadIdx.x;
  int n = idx >> 6, c = idx & 63;
  h[idx] = (c < IN_C) ? x[n * IN_C + c] : 0.0f;
}

// ---------------- CSR build ----------------
__global__ void k_zero_i(int* __restrict__ p) {
  p[blockIdx.x * 256 + threadIdx.x] = 0;
}

__global__ void k_hist(const int* __restrict__ ei, int* __restrict__ cnt) {
  int e = blockIdx.x * 256 + threadIdx.x;
  atomicAdd(&cnt[ei[NE + e]], 1);
}

__global__ void k_scan1(const int* __restrict__ cnt, int* __restrict__ off,
                        int* __restrict__ bsum) {
  __shared__ int s[256];
  int t = threadIdx.x;
  int i = blockIdx.x * 256 + t;
  int v = cnt[i];
  s[t] = v;
  __syncthreads();
  for (int d = 1; d < 256; d <<= 1) {
    int x = (t >= d) ? s[t - d] : 0;
    __syncthreads();
    s[t] += x;
    __syncthreads();
  }
  off[i] = s[t] - v;  // exclusive
  if (t == 255) bsum[blockIdx.x] = s[255];
}

__global__ void k_scan2(int* __restrict__ bsum) {
  __shared__ int s[320];
  int t = threadIdx.x;
  if (t < 320) s[t] = bsum[t];
  __syncthreads();
  if (t == 0) {
    int run = 0;
    for (int i = 0; i < 320; ++i) { int x = s[i]; s[i] = run; run += x; }
  }
  __syncthreads();
  if (t < 320) bsum[t] = s[t];
}

__global__ void k_scan3(int* __restrict__ off, const int* __restrict__ bsum) {
  int i = blockIdx.x * 256 + threadIdx.x;
  off[i] += bsum[blockIdx.x];
}

// scatter edges into CSR slots; off[n] mutates into row-end pointer
__global__ void k_scatter(const int* __restrict__ ei, const float* __restrict__ ea,
                          int* __restrict__ off, int2* __restrict__ csr) {
  int e = blockIdx.x * 256 + threadIdx.x;
  int dst = ei[NE + e];
  int slot = atomicAdd(&off[dst], 1);
  csr[slot] = make_int2(ei[e], __float_as_int(ea[e]));
}

// ---------------- per-layer kernels ----------------

// m16 = bf16(h @ Wg) via MFMA; wave-per-16-node-group, B=Wg hoisted to regs
__global__ void __launch_bounds__(256) k_gemm_mfma(
    const float* __restrict__ h, const float* __restrict__ Wg,
    ushort* __restrict__ m16) {
  const int lane = threadIdx.x & 63;
  const int cl = lane & 15;
  const int quad = lane >> 4;
  // B[k=quad*8+j][n=cl] = Wg[k][ct*16+cl]; 4 col-tiles x 2 K-halves
  bf16x8 B[4][2];
#pragma unroll
  for (int ct = 0; ct < 4; ++ct)
#pragma unroll
    for (int kh = 0; kh < 2; ++kh) {
      bf16x8 b;
#pragma unroll
      for (int j = 0; j < 8; ++j)
        b[j] = (short)bf16r(Wg[(kh * 32 + quad * 8 + j) * 64 + ct * 16 + cl]);
      B[ct][kh] = b;
    }
  int g = (blockIdx.x * 256 + threadIdx.x) >> 6;  // wave id = node group
  const int nwaves = (gridDim.x * 256) >> 6;
  for (; g < NN / 16; g += nwaves) {
    const float* hp = h + (size_t)(g * 16 + cl) * 64 + quad * 8;
    bf16x8 a0 = packf4(*(const float4*)hp, *(const float4*)(hp + 4));
    bf16x8 a1 = packf4(*(const float4*)(hp + 32), *(const float4*)(hp + 36));
    ushort* mp = m16 + (size_t)(g * 16 + quad * 4) * 64 + cl;
#pragma unroll
    for (int ct = 0; ct < 4; ++ct) {
      f32x4 acc = {0.0f, 0.0f, 0.0f, 0.0f};
      acc = __builtin_amdgcn_mfma_f32_16x16x32_bf16(a0, B[ct][0], acc, 0, 0, 0);
      acc = __builtin_amdgcn_mfma_f32_16x16x32_bf16(a1, B[ct][1], acc, 0, 0, 0);
#pragma unroll
      for (int rg = 0; rg < 4; ++rg)
        mp[(size_t)rg * 64 + ct * 16] = bf16r(acc[rg]);
    }
  }
}

// aggr16[n] = bf16( sum over CSR row n of m16[src]*w ); minimal, occupancy-max
__global__ void k_aggregate(const int* __restrict__ off, const int* __restrict__ cnt,
                            const int2* __restrict__ csr, const ushort* __restrict__ m16,
                            ushort* __restrict__ aggr16) {
  const int lane = threadIdx.x & 63;
  int wv = (blockIdx.x * 256 + threadIdx.x) >> 6;
  const int nw = (gridDim.x * 256) >> 6;
  for (int n = wv; n < NN; n += nw) {
    const int r1 = __builtin_amdgcn_readfirstlane(off[n]);  // row end
    const int c = __builtin_amdgcn_readfirstlane(cnt[n]);
    const int r0 = r1 - c;
    int2 ed = make_int2(0, 0);
    if (lane < c) ed = csr[r0 + lane];
    const int cc = c > 64 ? 64 : c;
    float acc = 0.0f;
    int i = 0;
    for (; i + 8 <= cc; i += 8) {
      int s0 = __builtin_amdgcn_readlane(ed.x, i + 0);
      int s1 = __builtin_amdgcn_readlane(ed.x, i + 1);
      int s2 = __builtin_amdgcn_readlane(ed.x, i + 2);
      int s3 = __builtin_amdgcn_readlane(ed.x, i + 3);
      int s4 = __builtin_amdgcn_readlane(ed.x, i + 4);
      int s5 = __builtin_amdgcn_readlane(ed.x, i + 5);
      int s6 = __builtin_amdgcn_readlane(ed.x, i + 6);
      int s7 = __builtin_amdgcn_readlane(ed.x, i + 7);
      float m0 = bf16f(m16[(size_t)s0 * 64 + lane]);
      float m1 = bf16f(m16[(size_t)s1 * 64 + lane]);
      float m2 = bf16f(m16[(size_t)s2 * 64 + lane]);
      float m3 = bf16f(m16[(size_t)s3 * 64 + lane]);
      float m4 = bf16f(m16[(size_t)s4 * 64 + lane]);
      float m5 = bf16f(m16[(size_t)s5 * 64 + lane]);
      float m6 = bf16f(m16[(size_t)s6 * 64 + lane]);
      float m7 = bf16f(m16[(size_t)s7 * 64 + lane]);
      acc = fmaf(m0, __int_as_float(__builtin_amdgcn_readlane(ed.y, i + 0)), acc);
      acc = fmaf(m1, __int_as_float(__builtin_amdgcn_readlane(ed.y, i + 1)), acc);
      acc = fmaf(m2, __int_as_float(__builtin_amdgcn_readlane(ed.y, i + 2)), acc);
      acc = fmaf(m3, __int_as_float(__builtin_amdgcn_readlane(ed.y, i + 3)), acc);
      acc = fmaf(m4, __int_as_float(__builtin_amdgcn_readlane(ed.y, i + 4)), acc);
      acc = fmaf(m5, __int_as_float(__builtin_amdgcn_readlane(ed.y, i + 5)), acc);
      acc = fmaf(m6, __int_as_float(__builtin_amdgcn_readlane(ed.y, i + 6)), acc);
      acc = fmaf(m7, __int_as_float(__builtin_amdgcn_readlane(ed.y, i + 7)), acc);
    }
    for (; i < cc; ++i) {
      int src = __builtin_amdgcn_readlane(ed.x, i);
      float wgt = __int_as_float(__builtin_amdgcn_readlane(ed.y, i));
      acc = fmaf(bf16f(m16[(size_t)src * 64 + lane]), wgt, acc);
    }
    for (int j = 64; j < c; ++j) {  // rare overflow
      int2 e2 = csr[r0 + j];
      acc = fmaf(bf16f(m16[(size_t)e2.x * 64 + lane]), __int_as_float(e2.y), acc);
    }
    aggr16[(size_t)n * 64 + lane] = bf16r(acc);
  }
}

// GRU via MFMA: gi = aggr@wih.T, gh = h@whh.T, gates, h update.
__global__ void __launch_bounds__(256) k_gru_mfma(
    const ushort* __restrict__ aggr16, float* __restrict__ h,
    const float* __restrict__ wih, const float* __restrict__ whh,
    const float* __restrict__ bih, const float* __restrict__ bhh) {
  const int lane = threadIdx.x & 63;
  const int w = threadIdx.x >> 6;  // 0..3
  const int cl = lane & 15;
  const int quad = lane >> 4;
  const int c = w * 16 + cl;       // gate col 0..63

  bf16x8 BI[3][2], BH[3][2];
#pragma unroll
  for (int g3 = 0; g3 < 3; ++g3) {
    const float* wi = wih + (size_t)(g3 * 64 + c) * 64;
    const float* wh = whh + (size_t)(g3 * 64 + c) * 64;
#pragma unroll
    for (int kh = 0; kh < 2; ++kh) {
      const float* p = wi + kh * 32 + quad * 8;
      BI[g3][kh] = packf4(*(const float4*)p, *(const float4*)(p + 4));
      const float* q = wh + kh * 32 + quad * 8;
      BH[g3][kh] = packf4(*(const float4*)q, *(const float4*)(q + 4));
    }
  }
  const float br = bih[c] + bhh[c];
  const float bz = bih[64 + c] + bhh[64 + c];
  const float bni = bih[128 + c];
  const float bnh = bhh[128 + c];

  const int ngroups = NN / 16;  // 5120
  for (int g = blockIdx.x; g < ngroups; g += gridDim.x) {
    const size_t arow = (size_t)(g * 16 + cl) * 64 + quad * 8;
    bf16x8 a0 = *(const bf16x8*)(aggr16 + arow);
    bf16x8 a1 = *(const bf16x8*)(aggr16 + arow + 32);
    const float* hp = h + arow;
    bf16x8 h0 = packf4(*(const float4*)hp, *(const float4*)(hp + 4));
    bf16x8 h1 = packf4(*(const float4*)(hp + 32), *(const float4*)(hp + 36));
    float hv[4];
    const size_t obase = (size_t)(g * 16 + quad * 4) * 64 + c;
#pragma unroll
    for (int rg = 0; rg < 4; ++rg) hv[rg] = h[obase + (size_t)rg * 64];
    __syncthreads();  // all h reads done before any wave stores h

    f32x4 zero = {0.0f, 0.0f, 0.0f, 0.0f};
    f32x4 aR = zero, aZ = zero, aN = zero, hR = zero, hZ = zero, hN = zero;
    aR = __builtin_amdgcn_mfma_f32_16x16x32_bf16(a0, BI[0][0], aR, 0, 0, 0);
    aR = __builtin_amdgcn_mfma_f32_16x16x32_bf16(a1, BI[0][1], aR, 0, 0, 0);
    aZ = __builtin_amdgcn_mfma_f32_16x16x32_bf16(a0, BI[1][0], aZ, 0, 0, 0);
    aZ = __builtin_amdgcn_mfma_f32_16x16x32_bf16(a1, BI[1][1], aZ, 0, 0, 0);
    aN = __builtin_amdgcn_mfma_f32_16x16x32_bf16(a0, BI[2][0], aN, 0, 0, 0);
    aN = __builtin_amdgcn_mfma_f32_16x16x32_bf16(a1, BI[2][1], aN, 0, 0, 0);
    hR = __builtin_amdgcn_mfma_f32_16x16x32_bf16(h0, BH[0][0], hR, 0, 0, 0);
    hR = __builtin_amdgcn_mfma_f32_16x16x32_bf16(h1, BH[0][1], hR, 0, 0, 0);
    hZ = __builtin_amdgcn_mfma_f32_16x16x32_bf16(h0, BH[1][0], hZ, 0, 0, 0);
    hZ = __builtin_amdgcn_mfma_f32_16x16x32_bf16(h1, BH[1][1], hZ, 0, 0, 0);
    hN = __builtin_amdgcn_mfma_f32_16x16x32_bf16(h0, BH[2][0], hN, 0, 0, 0);
    hN = __builtin_amdgcn_mfma_f32_16x16x32_bf16(h1, BH[2][1], hN, 0, 0, 0);

#pragma unroll
    for (int rg = 0; rg < 4; ++rg) {
      float r = sigmoidf_(aR[rg] + hR[rg] + br);
      float z = sigmoidf_(aZ[rg] + hZ[rg] + bz);
      float nv = tanhf_(aN[rg] + bni + r * (hN[rg] + bnh));
      h[obase + (size_t)rg * 64] = (1.0f - z) * nv + z * hv[rg];
    }
  }
}

// MLP1 via MFMA: part[sl][bs][c] = A-slice @ W1.T-slice
// grid: 512 = 32 batch-groups(16 rows) x 16 K-slices(640 = e-planes {2sl,2sl+1})
__global__ void __launch_bounds__(256) k_mlp1_mfma(
    const float* __restrict__ h, const float* __restrict__ W1,
    float* __restrict__ part) {
  const int lane = threadIdx.x & 63;
  const int w = threadIdx.x >> 6;
  const int cl = lane & 15;
  const int quad = lane >> 4;
  const int bg = blockIdx.x >> 4;      // 0..31
  const int sl = blockIdx.x & 15;      // 0..15
  const int bs0 = bg * 16;
  const int c = w * 16 + cl;
  f32x4 acc = {0.0f, 0.0f, 0.0f, 0.0f};
#pragma unroll
  for (int e2 = 0; e2 < 2; ++e2) {
    const int e = sl * 2 + e2;
#pragma unroll
    for (int g = 0; g < 5; ++g) {
      // A row m=cl -> node n = (bs0+cl)*160 + g*32 + e; k = f (contiguous)
      const float* hp = h + ((size_t)(bs0 + cl) * 160 + g * 32 + e) * 64 + quad * 8;
      bf16x8 a0 = packf4(*(const float4*)hp, *(const float4*)(hp + 4));
      bf16x8 a1 = packf4(*(const float4*)(hp + 32), *(const float4*)(hp + 36));
      const int kbase = e * 320 + g * 64;
      const float* wp = W1 + (size_t)c * KTOT + kbase + quad * 8;
      bf16x8 b0 = packf4(*(const float4*)wp, *(const float4*)(wp + 4));
      bf16x8 b1 = packf4(*(const float4*)(wp + 32), *(const float4*)(wp + 36));
      acc = __builtin_amdgcn_mfma_f32_16x16x32_bf16(a0, b0, acc, 0, 0, 0);
      acc = __builtin_amdgcn_mfma_f32_16x16x32_bf16(a1, b1, acc, 0, 0, 0);
    }
  }
  float* pp = part + ((size_t)sl * BSZ + bs0 + quad * 4) * 64 + c;
#pragma unroll
  for (int rg = 0; rg < 4; ++rg) pp[(size_t)rg * 64] = acc[rg];
}

// sum 16 slice-partials, +b1, relu -> 32 -> 16 -> 3 -> softmax; wave-per-row
__global__ void k_tail(const float* __restrict__ part, const float* __restrict__ b1,
                       const float* __restrict__ W2, const float* __restrict__ b2,
                       const float* __restrict__ W3, const float* __restrict__ b3,
                       const float* __restrict__ W4, const float* __restrict__ b4,
                       float* __restrict__ out) {
  const int lane = threadIdx.x & 63;
  const int bs = blockIdx.x * 4 + (threadIdx.x >> 6);
  float zp = 0.0f;
#pragma unroll
  for (int s = 0; s < NSLICE; ++s) zp += part[((size_t)s * BSZ + bs) * 64 + lane];
  float zv = fmaxf(zp + b1[lane], 0.0f);
  const int c2 = lane & 31;
  float acc2 = b2[c2];
#pragma unroll
  for (int k = 0; k < 64; ++k) acc2 = fmaf(bcast(zv, k), W2[c2 * 64 + k], acc2);
  acc2 = fmaxf(acc2, 0.0f);
  const int c3 = lane & 15;
  float acc3 = b3[c3];
#pragma unroll
  for (int k = 0; k < 32; ++k) acc3 = fmaf(bcast(acc2, k), W3[c3 * 32 + k], acc3);
  acc3 = fmaxf(acc3, 0.0f);
  float l0 = b4[0], l1 = b4[1], l2 = b4[2];
#pragma unroll
  for (int k = 0; k < 16; ++k) {
    float v = bcast(acc3, k);
    l0 = fmaf(v, W4[k], l0);
    l1 = fmaf(v, W4[16 + k], l1);
    l2 = fmaf(v, W4[32 + k], l2);
  }
  float mx = fmaxf(l0, fmaxf(l1, l2));
  float e0 = __expf(l0 - mx), e1 = __expf(l1 - mx), e2 = __expf(l2 - mx);
  float inv = 1.0f / (e0 + e1 + e2);
  if (lane == 0) {
    out[bs * 3 + 0] = e0 * inv;
    out[bs * 3 + 1] = e1 * inv;
    out[bs * 3 + 2] = e2 * inv;
  }
}

extern "C" void kernel_launch(void* const* d_in, const int* in_sizes, int n_in,
                              void* d_out, int out_size, void* d_ws, size_t ws_size,
                              hipStream_t stream) {
  const float* x = (const float*)d_in[0];
  const int* ei = (const int*)d_in[1];
  const float* ea = (const float*)d_in[2];
  const float* Wg = (const float*)d_in[3];
  const float* wih = (const float*)d_in[4];
  const float* whh = (const float*)d_in[5];
  const float* bih = (const float*)d_in[6];
  const float* bhh = (const float*)d_in[7];
  const float* W1 = (const float*)d_in[8];
  const float* b1 = (const float*)d_in[9];
  const float* W2 = (const float*)d_in[10];
  const float* b2 = (const float*)d_in[11];
  const float* W3 = (const float*)d_in[12];
  const float* b3 = (const float*)d_in[13];
  const float* W4 = (const float*)d_in[14];
  const float* b4 = (const float*)d_in[15];
  float* out = (float*)d_out;

  // workspace layout
  float* h = (float*)d_ws;                          // NN*64 f32
  float* part = h + (size_t)NN * 64;                // NSLICE*BSZ*64 f32
  int* cnt = (int*)(part + (size_t)NSLICE * BSZ * 64);  // NN
  int* off = cnt + NN;                              // NN
  int* bsum = off + NN;                             // 512
  int2* csr = (int2*)(bsum + 512);                  // NE int2
  ushort* m16 = (ushort*)(csr + NE);                // NN*64
  ushort* aggr16 = m16 + (size_t)NN * 64;           // NN*64

  // --- CSR build (once per launch) ---
  k_zero_i<<<NN / 256, 256, 0, stream>>>(cnt);
  k_hist<<<NE / 256, 256, 0, stream>>>(ei, cnt);
  k_scan1<<<NN / 256, 256, 0, stream>>>(cnt, off, bsum);
  k_scan2<<<1, 512, 0, stream>>>(bsum);
  k_scan3<<<NN / 256, 256, 0, stream>>>(off, bsum);
  k_scatter<<<NE / 256, 256, 0, stream>>>(ei, ea, off, csr);  // off -> row ends

  k_init<<<NN * 64 / 256, 256, 0, stream>>>(x, h);
  for (int layer = 0; layer < 2; ++layer) {
    k_gemm_mfma<<<1280, 256, 0, stream>>>(h, Wg + layer * 64 * 64, m16);
    k_aggregate<<<2048, 256, 0, stream>>>(off, cnt, csr, m16, aggr16);
    k_gru_mfma<<<1280, 256, 0, stream>>>(aggr16, h, wih, whh, bih, bhh);
  }
  k_mlp1_mfma<<<512, 256, 0, stream>>>(h, W1, part);
  k_tail<<<BSZ / 4, 256, 0, stream>>>(part, b1, W2, b2, W3, b3, W4, b4, out);
}